// Round 4
// baseline (4548.388 us; speedup 1.0000x reference)
//
#include <hip/hip_runtime.h>
#include <stdint.h>

// Dataflow LSTM with private-line signaling, MI355X.
// Workers: 128 WGs. grp0 = L0 (64 WGs): gates0 = [x_t | h0_{t-1}] @ [Wx0|Wh0]^T (K=1536).
//          grp1 = L1 (64 WGs): gates1 = [h0_t | h1_{t-1}] @ [Wx1|Wh1]^T (K=2048).
// Relays: WG 128 (for h0), WG 129 (for h1). Each relay polls 64 producer flag
// lines (one lane per line), then fans out step-complete to per-consumer
// private release lines. Every sync line has exactly 1 writer + 1 poller
// (producer flags: 1 writer + 1 relay lane) -> no same-line contention.
// All cross-WG data via sc1 write-through (RELAXED agent atomics); consumers
// read fresh unique addresses with normal cached loads (cold miss -> MALL hit).
// f-gate dead (reference quirk): only [i|g|o] = 48 gate rows per 16 units.
// Cell state lives in registers (same thread owns same (m,u) all 256 steps).

#define T_STEPS 256
#define HDIM    1024
#define NB      64
#define INDIM   512
#define NWORK   128
#define NWG     130
#define TPB     256

typedef _Float16 f16;
typedef __attribute__((ext_vector_type(8))) _Float16 f16x8;
typedef __attribute__((ext_vector_type(4))) float    f32x4;

// ws byte offsets
#define FLG_OFF 0
#define WL0_OFF 32768          // f16 [3072][1536]  rows=[i|g|o]x16 per ug, cols=[Wx0|Wh0]
#define WL1_OFF 9469952        // f16 [3072][2048]  cols=[Wx1|Wh1]
#define XB_OFF  22052864       // f16 [256][64][512]   x time-major
#define H0_OFF  38830080       // f16 [257][64][1024]  slot t = h0_{t-1}
#define H1_OFF  72515584       // f16 [257][64][1024]  slot t = h1_{t-1}
// end 106201088 bytes

__device__ __forceinline__ float sigm(float x)     { return 1.0f / (1.0f + __expf(-x)); }
__device__ __forceinline__ float tanhfast(float x) { float e = __expf(2.0f * x); return 1.0f - 2.0f / (e + 1.0f); }

__device__ __forceinline__ int* FLN(char* ws, int byteoff) { return (int*)(ws + FLG_OFF + byteoff); }
// line map (64B granularity): proCnt @0; FP[g][p] @1024+(g*64+p)*64;
// R0S[c] @9216+c*64 ; R0B[c] @13312+c*64 ; R1S[c] @17408+c*64
#define FP_LN(g,p)  (1024 + ((g) * 64 + (p)) * 64)
#define R0S_LN(c)   (9216  + (c) * 64)
#define R0B_LN(c)   (13312 + (c) * 64)
#define R1S_LN(c)   (17408 + (c) * 64)

__device__ __forceinline__ void sig_st(int* p, int v) {
  __hip_atomic_store(p, v, __ATOMIC_RELAXED, __HIP_MEMORY_SCOPE_AGENT);
}
__device__ __forceinline__ int sig_ld(int* p) {
  return __hip_atomic_load(p, __ATOMIC_RELAXED, __HIP_MEMORY_SCOPE_AGENT);
}
__device__ __forceinline__ void wait_ge(int* p, int v) {
  while (sig_ld(p) < v) __builtin_amdgcn_s_sleep(1);
  __atomic_signal_fence(__ATOMIC_ACQUIRE);
}
__device__ __forceinline__ void st2h(f16* p, float a, float b) {
  union { f16 h[2]; uint32_t u; } cc; cc.h[0] = (f16)a; cc.h[1] = (f16)b;
  __hip_atomic_store((uint32_t*)p, cc.u, __ATOMIC_RELAXED, __HIP_MEMORY_SCOPE_AGENT);
}

__global__ __launch_bounds__(TPB) void lstm_pers(
    const float* __restrict__ x,
    const float* __restrict__ Wx0, const float* __restrict__ Wh0,
    const float* __restrict__ b0,  const float* __restrict__ Wc0,
    const float* __restrict__ Wx1, const float* __restrict__ Wh1,
    const float* __restrict__ b1,  const float* __restrict__ Wc1,
    float* __restrict__ out, char* __restrict__ ws)
{
  f16* WL0 = (f16*)(ws + WL0_OFF);
  f16* WL1 = (f16*)(ws + WL1_OFF);
  f16* XB  = (f16*)(ws + XB_OFF);
  f16* H0  = (f16*)(ws + H0_OFF);
  f16* H1  = (f16*)(ws + H1_OFF);

  __shared__ float lds[4][64][49];

  const int tid  = threadIdx.x;
  const int wg   = blockIdx.x;
  const int gtid = wg * TPB + tid;
  const int GSZ  = NWG * TPB;

  // ---------------- prologue: pack weights/x as f16 (sc1 write-through) ----------------
  for (int idx = gtid; idx < 3072 * 768; idx += GSZ) {           // WL0 = [Wx0|Wh0]
    int r = idx / 768, c2 = (idx - r * 768) << 1;
    int g = r / 48, w = r - g * 48, gate = w >> 4, j = w & 15;
    int R = g * 16 + j + (gate == 1 ? 2048 : (gate == 2 ? 3072 : 0));
    float v0, v1;
    if (c2 < INDIM) { v0 = Wx0[R * INDIM + c2];          v1 = Wx0[R * INDIM + c2 + 1]; }
    else            { v0 = Wh0[R * HDIM + c2 - INDIM];   v1 = Wh0[R * HDIM + c2 - INDIM + 1]; }
    st2h(&WL0[(size_t)r * 1536 + c2], v0, v1);
  }
  for (int idx = gtid; idx < 3072 * 1024; idx += GSZ) {          // WL1 = [Wx1|Wh1]
    int r = idx >> 10, c2 = (idx & 1023) << 1;
    int g = r / 48, w = r - g * 48, gate = w >> 4, j = w & 15;
    int R = g * 16 + j + (gate == 1 ? 2048 : (gate == 2 ? 3072 : 0));
    float v0, v1;
    if (c2 < HDIM) { v0 = Wx1[R * HDIM + c2];         v1 = Wx1[R * HDIM + c2 + 1]; }
    else           { v0 = Wh1[R * HDIM + c2 - HDIM];  v1 = Wh1[R * HDIM + c2 - HDIM + 1]; }
    st2h(&WL1[(size_t)idx << 1], v0, v1);
  }
  for (int idx = gtid; idx < T_STEPS * NB * 256; idx += GSZ) {   // x pack, time-major
    int t = idx >> 14, n = (idx >> 8) & 63, i2 = (idx & 255) << 1;
    const float* src = x + (size_t)n * (T_STEPS * INDIM) + (size_t)t * INDIM + i2;
    st2h(&XB[(size_t)idx << 1], src[0], src[1]);
  }

  // one-time grid barrier (contended line acceptable once)
  __builtin_amdgcn_s_waitcnt(0);
  __syncthreads();
  if (tid == 0) {
    int* pc = FLN(ws, 0);
    __hip_atomic_fetch_add(pc, 1, __ATOMIC_RELAXED, __HIP_MEMORY_SCOPE_AGENT);
    wait_ge(pc, NWG);
  }
  __syncthreads();

  // ---------------- relay WGs ----------------
  if (wg >= NWORK) {
    if (tid >= 64) return;
    const int g = wg - NWORK;
    int* fp = FLN(ws, FP_LN(g, tid));
    int cur = 0;
    while (cur < T_STEPS) {
      int v = sig_ld(fp);
      if (__all(v >= cur + 1)) {
        ++cur;
        if (g == 0) { sig_st(FLN(ws, R0S_LN(tid)), cur); sig_st(FLN(ws, R0B_LN(tid)), cur); }
        else        { sig_st(FLN(ws, R1S_LN(tid)), cur); }
      } else {
        __builtin_amdgcn_s_sleep(1);
      }
    }
    return;
  }

  // ---------------- worker WGs ----------------
  const int grp  = wg >> 6;      // 0=L0, 1=L1
  const int ug   = wg & 63;      // 16-unit group
  const int lane = tid & 63;
  const int wv   = tid >> 6;
  const int quad = lane >> 4;
  const int lr   = lane & 15;

  const f16* Wm = grp ? WL1 : WL0;
  const int  K  = grp ? 2048 : 1536;
  const int  Kq = K >> 2;
  const f16* w0 = Wm + (size_t)(ug * 48 +  0 + lr) * K + wv * Kq + quad * 8;
  const f16* w1 = Wm + (size_t)(ug * 48 + 16 + lr) * K + wv * Kq + quad * 8;
  const f16* w2 = Wm + (size_t)(ug * 48 + 32 + lr) * K + wv * Kq + quad * 8;

  const float* bb = grp ? b1 : b0;
  const float* wc = grp ? Wc1 : Wc0;
  int* myFP  = FLN(ws, FP_LN(grp, ug));
  int* wSelf = grp ? FLN(ws, R1S_LN(ug)) : FLN(ws, R0S_LN(ug));
  int* wCross = grp ? FLN(ws, R0B_LN(ug)) : nullptr;

  float creg[4] = {0.f, 0.f, 0.f, 0.f};   // cell state, register-resident

  for (int t = 0; t < T_STEPS; ++t) {
    if (tid == 0) {
      if (grp) { wait_ge(wCross, t + 1); wait_ge(wSelf, t); }
      else     { wait_ge(wSelf, t); }
    }
    __syncthreads();

    // A = [seg0 | seg1]
    const f16 *s0p, *s1p; int s0len, s0sh;
    if (grp == 0) { s0p = XB + (size_t)t * NB * INDIM;       s0len = INDIM; s0sh = 9;
                    s1p = H0 + (size_t)t * NB * HDIM; }
    else          { s0p = H0 + (size_t)(t + 1) * NB * HDIM;  s0len = HDIM;  s0sh = 10;
                    s1p = H1 + (size_t)t * NB * HDIM; }

    f32x4 acc[4][3];
#pragma unroll
    for (int mt = 0; mt < 4; ++mt)
#pragma unroll
      for (int nt = 0; nt < 3; ++nt)
        acc[mt][nt] = (f32x4){0.f, 0.f, 0.f, 0.f};

    int kend0 = s0len - wv * Kq;
    if (kend0 < 0) kend0 = 0;
    if (kend0 > Kq) kend0 = Kq;

    auto run_seg = [&](const f16* abase, int sh, int kk0, int kk1) {
      const f16* a0 = abase + ((size_t)(lr +  0) << sh) + quad * 8;
      const f16* a1 = abase + ((size_t)(lr + 16) << sh) + quad * 8;
      const f16* a2 = abase + ((size_t)(lr + 32) << sh) + quad * 8;
      const f16* a3 = abase + ((size_t)(lr + 48) << sh) + quad * 8;
#pragma unroll 4
      for (int kk = kk0; kk < kk1; kk += 32) {
        f16x8 A0 = *(const f16x8*)(a0 + kk);
        f16x8 A1 = *(const f16x8*)(a1 + kk);
        f16x8 A2 = *(const f16x8*)(a2 + kk);
        f16x8 A3 = *(const f16x8*)(a3 + kk);
        f16x8 B0 = *(const f16x8*)(w0 + kk);
        f16x8 B1 = *(const f16x8*)(w1 + kk);
        f16x8 B2 = *(const f16x8*)(w2 + kk);
        acc[0][0] = __builtin_amdgcn_mfma_f32_16x16x32_f16(A0, B0, acc[0][0], 0, 0, 0);
        acc[0][1] = __builtin_amdgcn_mfma_f32_16x16x32_f16(A0, B1, acc[0][1], 0, 0, 0);
        acc[0][2] = __builtin_amdgcn_mfma_f32_16x16x32_f16(A0, B2, acc[0][2], 0, 0, 0);
        acc[1][0] = __builtin_amdgcn_mfma_f32_16x16x32_f16(A1, B0, acc[1][0], 0, 0, 0);
        acc[1][1] = __builtin_amdgcn_mfma_f32_16x16x32_f16(A1, B1, acc[1][1], 0, 0, 0);
        acc[1][2] = __builtin_amdgcn_mfma_f32_16x16x32_f16(A1, B2, acc[1][2], 0, 0, 0);
        acc[2][0] = __builtin_amdgcn_mfma_f32_16x16x32_f16(A2, B0, acc[2][0], 0, 0, 0);
        acc[2][1] = __builtin_amdgcn_mfma_f32_16x16x32_f16(A2, B1, acc[2][1], 0, 0, 0);
        acc[2][2] = __builtin_amdgcn_mfma_f32_16x16x32_f16(A2, B2, acc[2][2], 0, 0, 0);
        acc[3][0] = __builtin_amdgcn_mfma_f32_16x16x32_f16(A3, B0, acc[3][0], 0, 0, 0);
        acc[3][1] = __builtin_amdgcn_mfma_f32_16x16x32_f16(A3, B1, acc[3][1], 0, 0, 0);
        acc[3][2] = __builtin_amdgcn_mfma_f32_16x16x32_f16(A3, B2, acc[3][2], 0, 0, 0);
      }
    };
    if (kend0 > 0)  run_seg(s0p + wv * Kq,         s0sh, 0,     kend0);
    if (kend0 < Kq) run_seg(s1p + wv * Kq - s0len, 10,   kend0, Kq);

    // cross-wave K-partial reduce via LDS
#pragma unroll
    for (int mt = 0; mt < 4; ++mt)
#pragma unroll
      for (int nt = 0; nt < 3; ++nt)
#pragma unroll
        for (int r = 0; r < 4; ++r)
          lds[wv][mt * 16 + quad * 4 + r][nt * 16 + lr] = acc[mt][nt][r];
    __syncthreads();

    // epilogue: gates -> nonlinear -> h (sc1 store), c in registers
    f16* Hdst = (grp == 0 ? H0 : H1) + (size_t)(t + 1) * NB * HDIM;
#pragma unroll
    for (int rep = 0; rep < 2; ++rep) {
      int idx2 = rep * TPB + tid;
      int m = idx2 >> 3, jp = (idx2 & 7) << 1;
      float hv2[2], cn2[2];
#pragma unroll
      for (int q = 0; q < 2; ++q) {
        int j = jp + q;
        int u = ug * 16 + j;
        float gi = lds[0][m][j]      + lds[1][m][j]      + lds[2][m][j]      + lds[3][m][j]      + bb[u];
        float gg = lds[0][m][16 + j] + lds[1][m][16 + j] + lds[2][m][16 + j] + lds[3][m][16 + j] + bb[2048 + u];
        float go = lds[0][m][32 + j] + lds[1][m][32 + j] + lds[2][m][32 + j] + lds[3][m][32 + j] + bb[3072 + u];
        float cold = creg[rep * 2 + q];
        float iv = sigm(gi + wc[u] * cold);            // i peephole Wc[0]
        float gv = tanhfast(gg);                       // g
        float ov = sigm(go + wc[2048 + u] * cold);     // o peephole Wc[2]
        cn2[q] = gv * (cold + iv);     // faithful: ct = g*c + i*g
        hv2[q] = ov * tanhfast(cold);  // faithful: uses OLD cell state
        creg[rep * 2 + q] = cn2[q];
      }
      int u0 = ug * 16 + jp;
      st2h(&Hdst[m * HDIM + u0], hv2[0], hv2[1]);
      if (grp == 1) {
        float2* o2 = (float2*)&out[(size_t)m * (T_STEPS * HDIM) + (size_t)t * HDIM + u0];
        *o2 = make_float2(hv2[0], hv2[1]);
        if (t == T_STEPS - 1) {
          float2* hf = (float2*)&out[(size_t)NB * T_STEPS * HDIM + m * HDIM + u0];
          *hf = make_float2(hv2[0], hv2[1]);
          float2* cf = (float2*)&out[(size_t)NB * T_STEPS * HDIM + NB * HDIM + m * HDIM + u0];
          *cf = make_float2(cn2[0], cn2[1]);
        }
      }
    }

    // drain sc1 stores, then signal private flag (single writer line)
    __builtin_amdgcn_s_waitcnt(0);
    __syncthreads();
    if (tid == 0) sig_st(myFP, t + 1);
  }
}

extern "C" void kernel_launch(void* const* d_in, const int* in_sizes, int n_in,
                              void* d_out, int out_size, void* d_ws, size_t ws_size,
                              hipStream_t stream) {
  const float* x   = (const float*)d_in[0];
  const float* Wx0 = (const float*)d_in[1];
  const float* Wh0 = (const float*)d_in[2];
  const float* b0  = (const float*)d_in[3];
  const float* Wc0 = (const float*)d_in[4];
  const float* Wx1 = (const float*)d_in[5];
  const float* Wh1 = (const float*)d_in[6];
  const float* b1  = (const float*)d_in[7];
  const float* Wc1 = (const float*)d_in[8];
  char* ws = (char*)d_ws;

  // ws re-poisoned before each timed launch: zero flags + initial h slots
  hipMemsetAsync(ws + FLG_OFF, 0, 32768, stream);           // all signal lines
  hipMemsetAsync(ws + H0_OFF, 0, NB * HDIM * 2, stream);    // h0_{-1} = 0 (slot 0)
  hipMemsetAsync(ws + H1_OFF, 0, NB * HDIM * 2, stream);    // h1_{-1} = 0 (slot 0)

  hipLaunchKernelGGL(lstm_pers, dim3(NWG), dim3(TPB), 0, stream,
                     x, Wx0, Wh0, b0, Wc0, Wx1, Wh1, b1, Wc1,
                     (float*)d_out, ws);
}